// Round 1
// baseline (87.880 us; speedup 1.0000x reference)
//
#include <hip/hip_runtime.h>
#include <stdint.h>

typedef unsigned short u16;
typedef __attribute__((ext_vector_type(4))) float f32x4;
typedef __attribute__((ext_vector_type(8))) short s16x8;

#define T_INV 10.0f

__device__ __forceinline__ u16 f2bf(float f) {
  uint32_t u = __float_as_uint(f);
  uint32_t r = (u + 0x7FFFu + ((u >> 16) & 1u)) >> 16;
  return (u16)r;
}

__device__ __forceinline__ void gload_lds16(const void* g, void* l) {
  __builtin_amdgcn_global_load_lds(
      (const __attribute__((address_space(1))) uint32_t*)(g),
      (__attribute__((address_space(3))) uint32_t*)(l),
      16, 0, 0);
}

// ---------------- kernel 1: per-row softmax tables ----------------
// P_lo[b][lo] = prod_{f=4..7} hot[b][f][digit]   (bf16)
// P_hi[b][hi] = prod_{f=0..3} hot[b][f][digit]   (f32)
__global__ __launch_bounds__(256) void k_tables(
    const float* __restrict__ x, const float* __restrict__ beta,
    u16* __restrict__ plo, float* __restrict__ phi)
{
  const int t = threadIdx.x;
  const int b = blockIdx.x * 64 + (t >> 2);
  const int q = t & 3;   // quarter of the 256-entry tables; also i0 / i4 digit

  float hot[8][4];
#pragma unroll
  for (int f = 0; f < 8; ++f) {
    float b0 = beta[f*3+0], b1 = beta[f*3+1], b2 = beta[f*3+2];
    float s0 = fminf(b0, fminf(b1, b2));
    float s2 = fmaxf(b0, fmaxf(b1, b2));
    float s1 = b0 + b1 + b2 - s0 - s2;
    float bv1 = -s0, bv2 = -(s0 + s1), bv3 = -(s0 + s1 + s2);
    float xf = x[b*8 + f];
    float l0 = (xf * 1.0f       ) * T_INV;
    float l1 = (xf * 2.0f + bv1) * T_INV;
    float l2 = (xf * 3.0f + bv2) * T_INV;
    float l3 = (xf * 4.0f + bv3) * T_INV;
    float mm = fmaxf(fmaxf(l0, l1), fmaxf(l2, l3));
    float e0 = __expf(l0 - mm), e1 = __expf(l1 - mm);
    float e2 = __expf(l2 - mm), e3 = __expf(l3 - mm);
    float inv = 1.0f / (e0 + e1 + e2 + e3);
    hot[f][0] = e0*inv; hot[f][1] = e1*inv; hot[f][2] = e2*inv; hot[f][3] = e3*inv;
  }

  // ---- P_hi, entries [q*64, q*64+64): i0 == q ----
  {
    float h23[16];
#pragma unroll
    for (int i2 = 0; i2 < 4; ++i2)
#pragma unroll
      for (int i3 = 0; i3 < 4; ++i3) h23[i2*4+i3] = hot[2][i2] * hot[3][i3];
    float h0q = hot[0][q];
    float* dst = phi + (size_t)b*256 + q*64;
#pragma unroll
    for (int i1 = 0; i1 < 4; ++i1) {
      float c01 = h0q * hot[1][i1];
#pragma unroll
      for (int j = 0; j < 16; j += 4) {
        f32x4 v;
        v.x = c01 * h23[j+0]; v.y = c01 * h23[j+1];
        v.z = c01 * h23[j+2]; v.w = c01 * h23[j+3];
        *(f32x4*)(dst + i1*16 + j) = v;
      }
    }
  }
  // ---- P_lo, entries [q*64, q*64+64): i4 == q ----
  {
    float h67[16];
#pragma unroll
    for (int i6 = 0; i6 < 4; ++i6)
#pragma unroll
      for (int i7 = 0; i7 < 4; ++i7) h67[i6*4+i7] = hot[6][i6] * hot[7][i7];
    float h4q = hot[4][q];
    u16* dst = plo + (size_t)b*256 + q*64;
#pragma unroll
    for (int i5 = 0; i5 < 4; ++i5) {
      float c45 = h4q * hot[5][i5];
#pragma unroll
      for (int j = 0; j < 16; j += 8) {
        s16x8 v;
#pragma unroll
        for (int e = 0; e < 8; ++e) v[e] = (short)f2bf(c45 * h67[j+e]);
        *(s16x8*)(dst + i5*16 + j) = v;
      }
    }
  }
}

// ---------------- kernel 1b: classifier fp32 [65536][128] -> bf16 CT [128][65536] ----------------
__global__ __launch_bounds__(256) void k_transpose(
    const float* __restrict__ cls, u16* __restrict__ ct)
{
  __shared__ float tile[64 * 132];   // pad: stride 132 floats = 528 B (16B-divisible)
  const int t = threadIdx.x;
  const int k0 = blockIdx.x * 64;
#pragma unroll
  for (int it = 0; it < 8; ++it) {
    int e = it * 1024 + t * 4;
    int r = e >> 7;
    int c = e & 127;
    f32x4 v = *(const f32x4*)(cls + (size_t)(k0 + r) * 128 + c);
    *(f32x4*)(tile + r * 132 + c) = v;
  }
  __syncthreads();
  const int c  = t >> 1;
  const int kh = t & 1;
  u16 vals[32];
#pragma unroll
  for (int j = 0; j < 32; ++j)
    vals[j] = f2bf(tile[(kh*32 + j) * 132 + c]);
  u16* dst = ct + (size_t)c * 65536 + k0 + kh * 32;
#pragma unroll
  for (int qq = 0; qq < 4; ++qq) {
    s16x8 v;
#pragma unroll
    for (int e2 = 0; e2 < 8; ++e2) v[e2] = (short)vals[qq*8 + e2];
    *(s16x8*)(dst + qq*8) = v;
  }
}

// ---------------- main kernel ----------------
// grid 256 = 4 M-tiles (256 rows) x 64 hi-groups (4 his each, K-chunk 1024)
// 512 threads = 8 waves; wave tile 64 rows x 64 cols of 16x16x32 bf16 MFMA
__global__ __launch_bounds__(512, 2) void k_main(
    const u16* __restrict__ plo, const float* __restrict__ phi,
    const u16* __restrict__ ct, float* __restrict__ out)
{
  __shared__ __align__(16) u16 Ab[2][8192];   // [buf][row*32 + slot*8 + e], 256 rows
  __shared__ __align__(16) u16 Bb[2][4096];   // [buf][c*32 + slot*8 + e], 128 cols
  __shared__ __align__(16) float Ph[1024];    // [row][h], 256 x 4

  const int wg  = blockIdx.x;
  const int xcd = wg & 7;
  const int idx = wg >> 3;
  const int hig = xcd * 8 + (idx >> 2);  // all 4 m-tiles of a hi-group on one XCD
  const int m   = idx & 3;

  const int t    = threadIdx.x;
  const int l    = t & 63;
  const int w    = t >> 6;
  const int lrow = l & 15;
  const int kg   = l >> 4;
  const int rbase = (w & 3) * 64;
  const int cbase = (w >> 2) * 64;

  if (t < 256) {
    f32x4 v = *(const f32x4*)(phi + (size_t)(m*256 + t) * 256 + hig * 4);
    *(f32x4*)(Ph + t * 4) = v;
  }

  const u16* ploM = plo + (size_t)m * 256 * 256;
  const int srow = t >> 2;   // staging row (+ r*128) / staging col
  const int ssl  = t & 3;    // staging slot

  f32x4 acc[4][4];
  f32x4 hacc[4][4];
#pragma unroll
  for (int i = 0; i < 4; ++i)
#pragma unroll
    for (int j = 0; j < 4; ++j) { acc[i][j] = (f32x4)0.0f; hacc[i][j] = (f32x4)0.0f; }

  auto stage = [&](int h, int ks, int buf) {
    // A: P_lo tile, rotation-swizzled slots: phys slot s holds granule (s - (row>>1))&3
#pragma unroll
    for (int r = 0; r < 2; ++r) {
      int row = r * 128 + srow;
      int g = (ssl - ((row >> 1) & 3)) & 3;
      gload_lds16(ploM + (size_t)row * 256 + ks * 32 + g * 8,
                  &Ab[buf][r * 4096 + t * 8]);
    }
    // B: CT tile for k0 = (hig*4+h)*256 + ks*32
    {
      int g = (ssl - ((srow >> 1) & 3)) & 3;
      int k0 = (hig * 4 + h) * 256 + ks * 32;
      gload_lds16(ct + (size_t)srow * 65536 + k0 + g * 8,
                  &Bb[buf][t * 8]);
    }
  };

  stage(0, 0, 0);
  __syncthreads();

#pragma unroll 1
  for (int h = 0; h < 4; ++h) {
#pragma unroll
    for (int ks = 0; ks < 8; ++ks) {
      const int buf = ks & 1;          // (h*8+ks)&1 == ks&1
      if (h < 3 || ks < 7) {
        int nks = (ks + 1) & 7;
        int nh  = h + (ks == 7);
        stage(nh, nks, buf ^ 1);
      }
      s16x8 afr[4], bfr[4];
#pragma unroll
      for (int mt = 0; mt < 4; ++mt) {
        int row = rbase + mt * 16 + lrow;
        int s = (kg + ((row >> 1) & 3)) & 3;
        afr[mt] = *(const s16x8*)&Ab[buf][row * 32 + s * 8];
      }
#pragma unroll
      for (int nt = 0; nt < 4; ++nt) {
        int c = cbase + nt * 16 + lrow;
        int s = (kg + ((c >> 1) & 3)) & 3;
        bfr[nt] = *(const s16x8*)&Bb[buf][c * 32 + s * 8];
      }
#pragma unroll
      for (int mt = 0; mt < 4; ++mt)
#pragma unroll
        for (int nt = 0; nt < 4; ++nt)
          hacc[mt][nt] = __builtin_amdgcn_mfma_f32_16x16x32_bf16(
              afr[mt], bfr[nt], hacc[mt][nt], 0, 0, 0);
      __syncthreads();
    }
    // fold hi h: acc += P_hi[row][hig*4+h] * hacc
#pragma unroll
    for (int mt = 0; mt < 4; ++mt) {
#pragma unroll
      for (int r = 0; r < 4; ++r) {
        float p = Ph[(rbase + mt * 16 + kg * 4 + r) * 4 + h];
#pragma unroll
        for (int nt = 0; nt < 4; ++nt)
          acc[mt][nt][r] += p * hacc[mt][nt][r];
      }
#pragma unroll
      for (int nt = 0; nt < 4; ++nt) hacc[mt][nt] = (f32x4)0.0f;
    }
  }

  // epilogue: atomic accumulate partials (64 hi-groups per output element)
  float* outM = out + (size_t)m * 256 * 128;
#pragma unroll
  for (int mt = 0; mt < 4; ++mt)
#pragma unroll
    for (int r = 0; r < 4; ++r) {
      int row = rbase + mt * 16 + kg * 4 + r;
#pragma unroll
      for (int nt = 0; nt < 4; ++nt) {
        int col = cbase + nt * 16 + lrow;
        atomicAdd(outM + (size_t)row * 128 + col, acc[mt][nt][r]);
      }
    }
}

extern "C" void kernel_launch(void* const* d_in, const int* in_sizes, int n_in,
                              void* d_out, int out_size, void* d_ws, size_t ws_size,
                              hipStream_t stream)
{
  const float* x    = (const float*)d_in[0];
  const float* beta = (const float*)d_in[1];
  const float* cls  = (const float*)d_in[2];
  float* out = (float*)d_out;

  u16*   ct  = (u16*)d_ws;                                   // 16,777,216 B
  u16*   plo = (u16*)((char*)d_ws + (16u << 20));            // 524,288 B
  float* phi = (float*)((char*)d_ws + (16u << 20) + 524288); // 1,048,576 B

  hipMemsetAsync(d_out, 0, (size_t)out_size * sizeof(float), stream);
  k_tables<<<16, 256, 0, stream>>>(x, beta, plo, phi);
  k_transpose<<<1024, 256, 0, stream>>>(cls, ct);
  k_main<<<256, 512, 0, stream>>>(plo, phi, ct, out);
}

// Round 2
// 53.594 us; speedup vs baseline: 1.6397x; 1.6397x over previous
//
#include <hip/hip_runtime.h>
#include <stdint.h>

typedef unsigned short u16;
typedef __attribute__((ext_vector_type(4))) float f32x4;
typedef __attribute__((ext_vector_type(2))) float f32x2;
typedef __attribute__((ext_vector_type(8))) short s16x8;

#define T_INV 10.0f

__device__ __forceinline__ u16 f2bf(float f) {
  uint32_t u = __float_as_uint(f);
  uint32_t r = (u + 0x7FFFu + ((u >> 16) & 1u)) >> 16;
  return (u16)r;
}

__device__ __forceinline__ void gload_lds16(const void* g, void* l) {
  __builtin_amdgcn_global_load_lds(
      (const __attribute__((address_space(1))) uint32_t*)(g),
      (__attribute__((address_space(3))) uint32_t*)(l),
      16, 0, 0);
}

// ---------------- kernel 1: per-row softmax tables ----------------
__global__ __launch_bounds__(256) void k_tables(
    const float* __restrict__ x, const float* __restrict__ beta,
    u16* __restrict__ plo, float* __restrict__ phi)
{
  const int t = threadIdx.x;
  const int b = blockIdx.x * 64 + (t >> 2);
  const int q = t & 3;

  float hot[8][4];
#pragma unroll
  for (int f = 0; f < 8; ++f) {
    float b0 = beta[f*3+0], b1 = beta[f*3+1], b2 = beta[f*3+2];
    float s0 = fminf(b0, fminf(b1, b2));
    float s2 = fmaxf(b0, fmaxf(b1, b2));
    float s1 = b0 + b1 + b2 - s0 - s2;
    float bv1 = -s0, bv2 = -(s0 + s1), bv3 = -(s0 + s1 + s2);
    float xf = x[b*8 + f];
    float l0 = (xf * 1.0f       ) * T_INV;
    float l1 = (xf * 2.0f + bv1) * T_INV;
    float l2 = (xf * 3.0f + bv2) * T_INV;
    float l3 = (xf * 4.0f + bv3) * T_INV;
    float mm = fmaxf(fmaxf(l0, l1), fmaxf(l2, l3));
    float e0 = __expf(l0 - mm), e1 = __expf(l1 - mm);
    float e2 = __expf(l2 - mm), e3 = __expf(l3 - mm);
    float inv = 1.0f / (e0 + e1 + e2 + e3);
    hot[f][0] = e0*inv; hot[f][1] = e1*inv; hot[f][2] = e2*inv; hot[f][3] = e3*inv;
  }

  {
    float h23[16];
#pragma unroll
    for (int i2 = 0; i2 < 4; ++i2)
#pragma unroll
      for (int i3 = 0; i3 < 4; ++i3) h23[i2*4+i3] = hot[2][i2] * hot[3][i3];
    float h0q = hot[0][q];
    float* dst = phi + (size_t)b*256 + q*64;
#pragma unroll
    for (int i1 = 0; i1 < 4; ++i1) {
      float c01 = h0q * hot[1][i1];
#pragma unroll
      for (int j = 0; j < 16; j += 4) {
        f32x4 v;
        v.x = c01 * h23[j+0]; v.y = c01 * h23[j+1];
        v.z = c01 * h23[j+2]; v.w = c01 * h23[j+3];
        *(f32x4*)(dst + i1*16 + j) = v;
      }
    }
  }
  {
    float h67[16];
#pragma unroll
    for (int i6 = 0; i6 < 4; ++i6)
#pragma unroll
      for (int i7 = 0; i7 < 4; ++i7) h67[i6*4+i7] = hot[6][i6] * hot[7][i7];
    float h4q = hot[4][q];
    u16* dst = plo + (size_t)b*256 + q*64;
#pragma unroll
    for (int i5 = 0; i5 < 4; ++i5) {
      float c45 = h4q * hot[5][i5];
#pragma unroll
      for (int j = 0; j < 16; j += 8) {
        s16x8 v;
#pragma unroll
        for (int e = 0; e < 8; ++e) v[e] = (short)f2bf(c45 * h67[j+e]);
        *(s16x8*)(dst + i5*16 + j) = v;
      }
    }
  }
}

// ---------------- kernel 1b: classifier fp32 [65536][128] -> bf16 CT [128][65536] ----------------
__global__ __launch_bounds__(256) void k_transpose(
    const float* __restrict__ cls, u16* __restrict__ ct)
{
  __shared__ float tile[64 * 132];
  const int t = threadIdx.x;
  const int k0 = blockIdx.x * 64;
#pragma unroll
  for (int it = 0; it < 8; ++it) {
    int e = it * 1024 + t * 4;
    int r = e >> 7;
    int c = e & 127;
    f32x4 v = *(const f32x4*)(cls + (size_t)(k0 + r) * 128 + c);
    *(f32x4*)(tile + r * 132 + c) = v;
  }
  __syncthreads();
  const int c  = t >> 1;
  const int kh = t & 1;
  u16 vals[32];
#pragma unroll
  for (int j = 0; j < 32; ++j)
    vals[j] = f2bf(tile[(kh*32 + j) * 132 + c]);
  u16* dst = ct + (size_t)c * 65536 + k0 + kh * 32;
#pragma unroll
  for (int qq = 0; qq < 4; ++qq) {
    s16x8 v;
#pragma unroll
    for (int e2 = 0; e2 < 8; ++e2) v[e2] = (short)vals[qq*8 + e2];
    *(s16x8*)(dst + qq*8) = v;
  }
}

// ---------------- main kernel ----------------
// grid 512 = 8 m-tiles (128 rows) x 64 hi-groups (4 his, K-chunk 1024)
// 512 threads / 8 waves; wave tile 64 rows x 32 cols of 16x16x32 bf16 MFMA
// epilogue: plain bf16 partial stores (no atomics)
__global__ __launch_bounds__(512, 4) void k_main(
    const u16* __restrict__ plo, const float* __restrict__ phi,
    const u16* __restrict__ ct, u16* __restrict__ pws)
{
  __shared__ __align__(16) u16 Ab[2][4096];   // 128 rows x 32 k (rot-swizzled slots)
  __shared__ __align__(16) u16 Bb[2][4096];   // 128 cols x 32 k
  __shared__ __align__(16) float Ph[512];     // 128 rows x 4 his

  const int wg  = blockIdx.x;
  const int xcd = wg & 7;
  const int idx = wg >> 3;
  const int hig = xcd * 8 + (idx >> 3);   // all 8 m-tiles of a hi-group on one XCD
  const int m   = idx & 7;

  const int t    = threadIdx.x;
  const int l    = t & 63;
  const int w    = t >> 6;
  const int lrow = l & 15;
  const int kg   = l >> 4;
  const int rbase = (w & 1) * 64;
  const int cbase = (w >> 1) * 32;

  if (t < 128) {
    f32x4 v = *(const f32x4*)(phi + (size_t)(m*128 + t) * 256 + hig * 4);
    *(f32x4*)(Ph + t * 4) = v;
  }

  const u16* ploM = plo + (size_t)m * 128 * 256;
  const int srow = t >> 2;
  const int ssl  = t & 3;
  const int sg   = (ssl - ((srow >> 1) & 3)) & 3;   // granule staged into this slot

  f32x4 acc[4][2], hacc[4][2];
#pragma unroll
  for (int i = 0; i < 4; ++i)
#pragma unroll
    for (int j = 0; j < 2; ++j) { acc[i][j] = (f32x4)0.0f; hacc[i][j] = (f32x4)0.0f; }

  auto stage = [&](int h, int ks, int buf) {
    gload_lds16(ploM + (size_t)srow * 256 + ks * 32 + sg * 8, &Ab[buf][t * 8]);
    int k0 = (hig * 4 + h) * 256 + ks * 32;
    gload_lds16(ct + (size_t)srow * 65536 + k0 + sg * 8, &Bb[buf][t * 8]);
  };

  stage(0, 0, 0);
  __syncthreads();

#pragma unroll 1
  for (int h = 0; h < 4; ++h) {
#pragma unroll
    for (int ks = 0; ks < 8; ++ks) {
      const int buf = ks & 1;
      if (h < 3 || ks < 7) {
        int nks = (ks + 1) & 7;
        int nh  = h + (ks == 7);
        stage(nh, nks, buf ^ 1);
      }
      s16x8 afr[4], bfr[2];
#pragma unroll
      for (int mt = 0; mt < 4; ++mt) {
        int row = rbase + mt * 16 + lrow;
        int s = (kg + ((row >> 1) & 3)) & 3;
        afr[mt] = *(const s16x8*)&Ab[buf][row * 32 + s * 8];
      }
#pragma unroll
      for (int nt = 0; nt < 2; ++nt) {
        int c = cbase + nt * 16 + lrow;
        int s = (kg + ((c >> 1) & 3)) & 3;
        bfr[nt] = *(const s16x8*)&Bb[buf][c * 32 + s * 8];
      }
#pragma unroll
      for (int mt = 0; mt < 4; ++mt)
#pragma unroll
        for (int nt = 0; nt < 2; ++nt)
          hacc[mt][nt] = __builtin_amdgcn_mfma_f32_16x16x32_bf16(
              afr[mt], bfr[nt], hacc[mt][nt], 0, 0, 0);
      __syncthreads();
    }
    // fold hi h: acc += P_hi[row][hig*4+h] * hacc
#pragma unroll
    for (int mt = 0; mt < 4; ++mt) {
#pragma unroll
      for (int r = 0; r < 4; ++r) {
        float p = Ph[(rbase + mt * 16 + kg * 4 + r) * 4 + h];
#pragma unroll
        for (int nt = 0; nt < 2; ++nt)
          acc[mt][nt][r] += p * hacc[mt][nt][r];
      }
#pragma unroll
      for (int nt = 0; nt < 2; ++nt) hacc[mt][nt] = (f32x4)0.0f;
    }
  }

  // epilogue: bf16 partial store, P[hig][1024][128]
  u16* dst = pws + ((size_t)hig * 1024 + (size_t)m * 128) * 128;
#pragma unroll
  for (int mt = 0; mt < 4; ++mt)
#pragma unroll
    for (int r = 0; r < 4; ++r) {
      int row = rbase + mt * 16 + kg * 4 + r;
#pragma unroll
      for (int nt = 0; nt < 2; ++nt) {
        int col = cbase + nt * 16 + lrow;
        dst[row * 128 + col] = f2bf(acc[mt][nt][r]);
      }
    }
}

// ---------------- reduce: out[e] = sum_hig P[hig][e] ----------------
__global__ __launch_bounds__(256) void k_reduce(
    const u16* __restrict__ p, float* __restrict__ out)
{
  const int g = blockIdx.x * 256 + threadIdx.x;   // 0..65535, 2 elems each
  const u16* src = p + (size_t)g * 2;
  float a0 = 0.0f, a1 = 0.0f;
#pragma unroll 8
  for (int hig = 0; hig < 64; ++hig) {
    uint32_t v = *(const uint32_t*)(src + (size_t)hig * 131072);
    a0 += __uint_as_float((v & 0xFFFFu) << 16);
    a1 += __uint_as_float(v & 0xFFFF0000u);
  }
  f32x2 o; o.x = a0; o.y = a1;
  *(f32x2*)(out + (size_t)g * 2) = o;
}

extern "C" void kernel_launch(void* const* d_in, const int* in_sizes, int n_in,
                              void* d_out, int out_size, void* d_ws, size_t ws_size,
                              hipStream_t stream)
{
  const float* x    = (const float*)d_in[0];
  const float* beta = (const float*)d_in[1];
  const float* cls  = (const float*)d_in[2];
  float* out = (float*)d_out;

  char* ws = (char*)d_ws;
  u16*   ct  = (u16*)ws;                               // 16,777,216 B
  u16*   plo = (u16*)(ws + (16u << 20));               //    524,288 B
  float* phi = (float*)(ws + (16u << 20) + 524288);    //  1,048,576 B
  u16*   pws = (u16*)(ws + (16u << 20) + 524288 + 1048576); // 16,777,216 B

  k_tables<<<16, 256, 0, stream>>>(x, beta, plo, phi);
  k_transpose<<<1024, 256, 0, stream>>>(cls, ct);
  k_main<<<512, 512, 0, stream>>>(plo, phi, ct, pws);
  k_reduce<<<256, 256, 0, stream>>>(pws, out);
}

// Round 3
// 49.422 us; speedup vs baseline: 1.7782x; 1.0844x over previous
//
#include <hip/hip_runtime.h>
#include <stdint.h>

typedef unsigned short u16;
typedef __attribute__((ext_vector_type(4))) float f32x4;
typedef __attribute__((ext_vector_type(2))) float f32x2;
typedef __attribute__((ext_vector_type(8))) short s16x8;

#define T_INV 10.0f

__device__ __forceinline__ u16 f2bf(float f) {
  uint32_t u = __float_as_uint(f);
  uint32_t r = (u + 0x7FFFu + ((u >> 16) & 1u)) >> 16;
  return (u16)r;
}

__device__ __forceinline__ void gload_lds16(const void* g, void* l) {
  __builtin_amdgcn_global_load_lds(
      (const __attribute__((address_space(1))) uint32_t*)(g),
      (__attribute__((address_space(3))) uint32_t*)(l),
      16, 0, 0);
}

// ---------------- kernel 1: per-row softmax tables ----------------
// plo[b][lo]  = prod_{f=4..7} hot[f][digit]      (bf16, [1024][256])
// phiT[hi][b] = prod_{f=0..3} hot[f][digit]      (f32, [256][1024], TRANSPOSED)
__global__ __launch_bounds__(256) void k_tables(
    const float* __restrict__ x, const float* __restrict__ beta,
    u16* __restrict__ plo, float* __restrict__ phiT)
{
  const int t = threadIdx.x;
  const int b = blockIdx.x * 64 + (t >> 2);
  const int q = t & 3;

  float hot[8][4];
#pragma unroll
  for (int f = 0; f < 8; ++f) {
    float b0 = beta[f*3+0], b1 = beta[f*3+1], b2 = beta[f*3+2];
    float s0 = fminf(b0, fminf(b1, b2));
    float s2 = fmaxf(b0, fmaxf(b1, b2));
    float s1 = b0 + b1 + b2 - s0 - s2;
    float bv1 = -s0, bv2 = -(s0 + s1), bv3 = -(s0 + s1 + s2);
    float xf = x[b*8 + f];
    float l0 = (xf * 1.0f       ) * T_INV;
    float l1 = (xf * 2.0f + bv1) * T_INV;
    float l2 = (xf * 3.0f + bv2) * T_INV;
    float l3 = (xf * 4.0f + bv3) * T_INV;
    float mm = fmaxf(fmaxf(l0, l1), fmaxf(l2, l3));
    float e0 = __expf(l0 - mm), e1 = __expf(l1 - mm);
    float e2 = __expf(l2 - mm), e3 = __expf(l3 - mm);
    float inv = 1.0f / (e0 + e1 + e2 + e3);
    hot[f][0] = e0*inv; hot[f][1] = e1*inv; hot[f][2] = e2*inv; hot[f][3] = e3*inv;
  }

  {
    float h23[16];
#pragma unroll
    for (int i2 = 0; i2 < 4; ++i2)
#pragma unroll
      for (int i3 = 0; i3 < 4; ++i3) h23[i2*4+i3] = hot[2][i2] * hot[3][i3];
    float h0q = hot[0][q];
#pragma unroll
    for (int i1 = 0; i1 < 4; ++i1) {
      float c01 = h0q * hot[1][i1];
#pragma unroll
      for (int j = 0; j < 16; ++j)
        phiT[(size_t)(q*64 + i1*16 + j) * 1024 + b] = c01 * h23[j];
    }
  }
  {
    float h67[16];
#pragma unroll
    for (int i6 = 0; i6 < 4; ++i6)
#pragma unroll
      for (int i7 = 0; i7 < 4; ++i7) h67[i6*4+i7] = hot[6][i6] * hot[7][i7];
    float h4q = hot[4][q];
    u16* dst = plo + (size_t)b*256 + q*64;
#pragma unroll
    for (int i5 = 0; i5 < 4; ++i5) {
      float c45 = h4q * hot[5][i5];
#pragma unroll
      for (int j = 0; j < 16; j += 8) {
        s16x8 v;
#pragma unroll
        for (int e = 0; e < 8; ++e) v[e] = (short)f2bf(c45 * h67[j+e]);
        *(s16x8*)(dst + i5*16 + j) = v;
      }
    }
  }
}

// ---------------- kernel 1b: classifier fp32 [65536][128] -> bf16 CT [128][65536] ----------------
__global__ __launch_bounds__(256) void k_transpose(
    const float* __restrict__ cls, u16* __restrict__ ct)
{
  __shared__ float tile[64 * 132];
  const int t = threadIdx.x;
  const int k0 = blockIdx.x * 64;
#pragma unroll
  for (int it = 0; it < 8; ++it) {
    int e = it * 1024 + t * 4;
    int r = e >> 7;
    int c = e & 127;
    f32x4 v = *(const f32x4*)(cls + (size_t)(k0 + r) * 128 + c);
    *(f32x4*)(tile + r * 132 + c) = v;
  }
  __syncthreads();
  const int c  = t >> 1;
  const int kh = t & 1;
  u16 vals[32];
#pragma unroll
  for (int j = 0; j < 32; ++j)
    vals[j] = f2bf(tile[(kh*32 + j) * 132 + c]);
  u16* dst = ct + (size_t)c * 65536 + k0 + kh * 32;
#pragma unroll
  for (int qq = 0; qq < 4; ++qq) {
    s16x8 v;
#pragma unroll
    for (int e2 = 0; e2 < 8; ++e2) v[e2] = (short)vals[qq*8 + e2];
    *(s16x8*)(dst + qq*8) = v;
  }
}

// ---------------- main kernel ----------------
// grid 512 = 8 m-tiles (128 rows) x 64 hi-groups (4 his, K-chunk 1024)
// 512 threads / 8 waves; wave tile 64 rows x 32 cols of 16x16x32 bf16 MFMA
// A (P_lo, 128x256 bf16) staged ONCE into 64KB static LDS; loop stages only B.
__global__ __launch_bounds__(512, 4) void k_main(
    const u16* __restrict__ plo, const float* __restrict__ phiT,
    const u16* __restrict__ ct, u16* __restrict__ pws)
{
  __shared__ __align__(16) u16 As[8][4096];   // [ks][row*32 + slot*8]  64KB static
  __shared__ __align__(16) u16 Bb[2][4096];   // [buf][col*32 + slot*8] 16KB dbuf

  const int wg  = blockIdx.x;
  const int xcd = wg & 7;
  const int idx = wg >> 3;
  const int hig = xcd * 8 + (idx >> 3);   // all 8 m-tiles of a hi-group on one XCD
  const int m   = idx & 7;

  const int t    = threadIdx.x;
  const int l    = t & 63;
  const int w    = t >> 6;
  const int lrow = l & 15;
  const int kg   = l >> 4;
  const int rbase = (w & 1) * 64;
  const int cbase = (w >> 1) * 32;

  const u16* ploM = plo + (size_t)m * 128 * 256;
  const int srow = t >> 2;
  const int ssl  = t & 3;
  const int sg   = (ssl - ((srow >> 1) & 3)) & 3;   // granule staged into this slot

  // ---- prologue: stage all of A (8 k-chunks), then first B ----
#pragma unroll
  for (int ks = 0; ks < 8; ++ks)
    gload_lds16(ploM + (size_t)srow * 256 + ks * 32 + sg * 8, &As[ks][t * 8]);

  auto stageB = [&](int h, int ks, int buf) {
    int k0 = (hig * 4 + h) * 256 + ks * 32;
    gload_lds16(ct + (size_t)srow * 65536 + k0 + sg * 8, &Bb[buf][t * 8]);
  };

  stageB(0, 0, 0);
  __syncthreads();

  f32x4 acc[4][2], hacc[4][2];
#pragma unroll
  for (int i = 0; i < 4; ++i)
#pragma unroll
    for (int j = 0; j < 2; ++j) { acc[i][j] = (f32x4)0.0f; hacc[i][j] = (f32x4)0.0f; }

#pragma unroll 1
  for (int h = 0; h < 4; ++h) {
#pragma unroll
    for (int ks = 0; ks < 8; ++ks) {
      const int buf = ks & 1;
      if (h < 3 || ks < 7) {
        int nks = (ks + 1) & 7;
        int nh  = h + (ks == 7);
        stageB(nh, nks, buf ^ 1);
      }
      s16x8 afr[4], bfr[2];
#pragma unroll
      for (int mt = 0; mt < 4; ++mt) {
        int row = rbase + mt * 16 + lrow;
        int s = (kg + ((row >> 1) & 3)) & 3;
        afr[mt] = *(const s16x8*)&As[ks][row * 32 + s * 8];
      }
#pragma unroll
      for (int nt = 0; nt < 2; ++nt) {
        int c = cbase + nt * 16 + lrow;
        int s = (kg + ((c >> 1) & 3)) & 3;
        bfr[nt] = *(const s16x8*)&Bb[buf][c * 32 + s * 8];
      }
#pragma unroll
      for (int mt = 0; mt < 4; ++mt)
#pragma unroll
        for (int nt = 0; nt < 2; ++nt)
          hacc[mt][nt] = __builtin_amdgcn_mfma_f32_16x16x32_bf16(
              afr[mt], bfr[nt], hacc[mt][nt], 0, 0, 0);
      __syncthreads();
    }
    // fold hi h: acc += phiT[hig*4+h][m*128+row] * hacc  (f32x4 L2 loads)
    const float* ph = phiT + (size_t)(hig * 4 + h) * 1024 + m * 128;
#pragma unroll
    for (int mt = 0; mt < 4; ++mt) {
      f32x4 p4 = *(const f32x4*)(ph + rbase + mt * 16 + kg * 4);
#pragma unroll
      for (int r = 0; r < 4; ++r) {
#pragma unroll
        for (int nt = 0; nt < 2; ++nt)
          acc[mt][nt][r] += p4[r] * hacc[mt][nt][r];
      }
#pragma unroll
      for (int nt = 0; nt < 2; ++nt) hacc[mt][nt] = (f32x4)0.0f;
    }
  }

  // epilogue: bf16 partial store, P[hig][1024][128]
  u16* dst = pws + ((size_t)hig * 1024 + (size_t)m * 128) * 128;
#pragma unroll
  for (int mt = 0; mt < 4; ++mt)
#pragma unroll
    for (int r = 0; r < 4; ++r) {
      int row = rbase + mt * 16 + kg * 4 + r;
#pragma unroll
      for (int nt = 0; nt < 2; ++nt) {
        int col = cbase + nt * 16 + lrow;
        dst[row * 128 + col] = f2bf(acc[mt][nt][r]);
      }
    }
}

// ---------------- reduce: out[e] = sum_hig P[hig][e] ----------------
__global__ __launch_bounds__(256) void k_reduce(
    const u16* __restrict__ p, float* __restrict__ out)
{
  const int g = blockIdx.x * 256 + threadIdx.x;   // 0..65535, 2 elems each
  const u16* src = p + (size_t)g * 2;
  float a0 = 0.0f, a1 = 0.0f;
#pragma unroll 8
  for (int hig = 0; hig < 64; ++hig) {
    uint32_t v = *(const uint32_t*)(src + (size_t)hig * 131072);
    a0 += __uint_as_float((v & 0xFFFFu) << 16);
    a1 += __uint_as_float(v & 0xFFFF0000u);
  }
  f32x2 o; o.x = a0; o.y = a1;
  *(f32x2*)(out + (size_t)g * 2) = o;
}

extern "C" void kernel_launch(void* const* d_in, const int* in_sizes, int n_in,
                              void* d_out, int out_size, void* d_ws, size_t ws_size,
                              hipStream_t stream)
{
  const float* x    = (const float*)d_in[0];
  const float* beta = (const float*)d_in[1];
  const float* cls  = (const float*)d_in[2];
  float* out = (float*)d_out;

  char* ws = (char*)d_ws;
  u16*   ct   = (u16*)ws;                               // 16,777,216 B
  u16*   plo  = (u16*)(ws + (16u << 20));               //    524,288 B
  float* phiT = (float*)(ws + (16u << 20) + 524288);    //  1,048,576 B
  u16*   pws  = (u16*)(ws + (16u << 20) + 524288 + 1048576); // 16,777,216 B

  k_tables<<<16, 256, 0, stream>>>(x, beta, plo, phiT);
  k_transpose<<<1024, 256, 0, stream>>>(cls, ct);
  k_main<<<512, 512, 0, stream>>>(plo, phiT, ct, pws);
  k_reduce<<<256, 256, 0, stream>>>(pws, out);
}